// Round 1
// baseline (311.420 us; speedup 1.0000x reference)
//
#include <hip/hip_runtime.h>
#include <hip/hip_bf16.h>

// MoE MLP (top-2 of 8 experts), T=4096 tokens, D=1024, W=1024.
// Pipeline: [transpose+cvt weights] -> [router fp32 + x->bf16 + expert lists]
//           -> [grouped GEMM1 (gather) + relu^2] -> [grouped GEMM2 + weighted atomic scatter]
// GEMM: m97-style 128x128 tile, BK=32, 16x16x32 bf16 MFMA, global_load_lds width 16,
// XOR-swizzled 16B granules so frag ds_read_b128 is 2-way-bank (free).

#define T_TOKENS 4096
#define DD 1024
#define EE 8
#define WW 1024
#define CAP 2048          // per-expert capacity (expected ~1024 +- ~100)
#define BM 128
#define BN 128
#define BK 32
#define MT (CAP / BM)     // 16 m-tiles max per expert
#define NT 8              // 1024/128 n-tiles

typedef short bf16x8 __attribute__((ext_vector_type(8)));
typedef float f32x4 __attribute__((ext_vector_type(4)));

__device__ __forceinline__ void gload_lds16(const void* g, void* l) {
  __builtin_amdgcn_global_load_lds((__attribute__((address_space(1))) void*)(g),
                                   (__attribute__((address_space(3))) void*)(l),
                                   16, 0, 0);
}

// ---------------- transpose + fp32->bf16 convert ----------------
// dst[r*dst_ld + c] = bf16(src[c*src_ld + r]), gridDim.z blocks offset by blk strides.
__global__ __launch_bounds__(256) void transpose_cvt(
    const float* __restrict__ src, __hip_bfloat16* __restrict__ dst,
    int src_ld, int dst_ld, long src_blk, long dst_blk)
{
  __shared__ float tile[32][33];
  const float* s = src + (long)blockIdx.z * src_blk;
  __hip_bfloat16* d = dst + (long)blockIdx.z * dst_blk;
  int tx = threadIdx.x, ty = threadIdx.y;
  int c0 = blockIdx.x * 32;   // dst col tile
  int r0 = blockIdx.y * 32;   // dst row tile
#pragma unroll
  for (int i = 0; i < 4; i++)
    tile[ty + 8 * i][tx] = s[(long)(c0 + ty + 8 * i) * src_ld + r0 + tx];
  __syncthreads();
#pragma unroll
  for (int i = 0; i < 4; i++)
    d[(long)(r0 + ty + 8 * i) * dst_ld + c0 + tx] =
        __float2bfloat16(tile[tx][ty + 8 * i]);
}

// ---------------- router: fp32 logits, sigmoid, top-2, expert lists ----------------
__global__ __launch_bounds__(256) void router_kernel(
    const float* __restrict__ x, const float* __restrict__ rw,
    __hip_bfloat16* __restrict__ xb, int* __restrict__ counts,
    int* __restrict__ idx, float* __restrict__ aw)
{
  int lane = threadIdx.x & 63;
  int wave = threadIdx.x >> 6;
  int t = blockIdx.x * 4 + wave;   // one wave per token
  const float* xrow = x + (size_t)t * DD;
  float acc[EE];
#pragma unroll
  for (int e = 0; e < EE; e++) acc[e] = 0.f;
#pragma unroll
  for (int i = 0; i < DD / 64; i++) {
    int d = lane + i * 64;
    float xv = xrow[d];
    xb[t * DD + d] = __float2bfloat16(xv);   // fused x -> bf16
#pragma unroll
    for (int e = 0; e < EE; e++) acc[e] += xv * rw[e * DD + d];
  }
#pragma unroll
  for (int e = 0; e < EE; e++) {
#pragma unroll
    for (int off = 32; off > 0; off >>= 1)
      acc[e] += __shfl_down(acc[e], off, 64);
  }
  if (lane == 0) {
    float p[EE];
#pragma unroll
    for (int e = 0; e < EE; e++) p[e] = 1.f / (1.f + expf(-acc[e]));
    // top-2, ties -> lowest index (matches jax.lax.top_k stable ordering)
    int e0 = 0; float b0 = p[0];
    for (int e = 1; e < EE; e++) if (p[e] > b0) { b0 = p[e]; e0 = e; }
    int e1 = -1; float b1 = -1.f;
    for (int e = 0; e < EE; e++) {
      if (e == e0) continue;
      if (p[e] > b1) { b1 = p[e]; e1 = e; }
    }
    float s = b0 + b1 + 1e-20f;
    float w0 = b0 / s, w1 = b1 / s;
    int s0 = atomicAdd(&counts[e0], 1);
    idx[e0 * CAP + s0] = t; aw[e0 * CAP + s0] = w0;
    int s1 = atomicAdd(&counts[e1], 1);
    idx[e1 * CAP + s1] = t; aw[e1 * CAP + s1] = w1;
  }
}

// ---------------- grouped GEMM1: h = gather(xb) @ W1_e, act = relu(h)^2 ----------------
__global__ __launch_bounds__(256) void gemm1_kernel(
    const __hip_bfloat16* __restrict__ xb, const __hip_bfloat16* __restrict__ w1t,
    const int* __restrict__ counts, const int* __restrict__ idx,
    __hip_bfloat16* __restrict__ act)
{
  __shared__ short As[BM * BK];
  __shared__ short Bs[BN * BK];
  int b = blockIdx.x;
  int e = b / (MT * NT);
  int rem = b % (MT * NT);
  int mt = rem / NT, nt = rem % NT;
  int n_e = counts[e];
  if (mt * BM >= n_e) return;

  int tid = threadIdx.x;
  int lane = tid & 63;
  int wave = __builtin_amdgcn_readfirstlane(tid >> 6);
  int wm = (wave >> 1) * 64, wn = (wave & 1) * 64;
  int m16 = lane & 15, qd = lane >> 4;

  // staging: 2 granules (16B) each of A and B per thread; LDS granule sg = i*256+tid
  const __hip_bfloat16* gA[2];
  const __hip_bfloat16* gB[2];
#pragma unroll
  for (int i = 0; i < 2; i++) {
    int sg = i * 256 + tid;
    int r = sg >> 2;
    int q = (sg & 3) ^ ((r >> 1) & 3);        // un-swizzle: logical k-granule
    int rowA = mt * BM + r;
    int slot = rowA < n_e - 1 ? rowA : n_e - 1;  // clamp tail rows to valid slot
    int tok = idx[e * CAP + slot];
    gA[i] = xb + tok * DD + q * 8;
    gB[i] = w1t + (e * WW + nt * BN + r) * DD + q * 8;
  }
  short* ldsA0 = As + (wave * 64) * 8;
  short* ldsA1 = As + (256 + wave * 64) * 8;
  short* ldsB0 = Bs + (wave * 64) * 8;
  short* ldsB1 = Bs + (256 + wave * 64) * 8;

  int aoff[4], boff[4];
#pragma unroll
  for (int i = 0; i < 4; i++) {
    int ra = wm + i * 16 + m16;
    aoff[i] = (ra * 4 + (qd ^ ((ra >> 1) & 3))) * 8;
    int rb = wn + i * 16 + m16;
    boff[i] = (rb * 4 + (qd ^ ((rb >> 1) & 3))) * 8;
  }

  f32x4 zero = {0.f, 0.f, 0.f, 0.f};
  f32x4 acc[4][4];
#pragma unroll
  for (int mi = 0; mi < 4; mi++)
#pragma unroll
    for (int ni = 0; ni < 4; ni++) acc[mi][ni] = zero;

  for (int k0 = 0; k0 < DD; k0 += BK) {
    gload_lds16(gA[0] + k0, ldsA0);
    gload_lds16(gA[1] + k0, ldsA1);
    gload_lds16(gB[0] + k0, ldsB0);
    gload_lds16(gB[1] + k0, ldsB1);
    __syncthreads();
    bf16x8 af[4], bfr[4];
#pragma unroll
    for (int i = 0; i < 4; i++) af[i] = *(const bf16x8*)(As + aoff[i]);
#pragma unroll
    for (int i = 0; i < 4; i++) bfr[i] = *(const bf16x8*)(Bs + boff[i]);
#pragma unroll
    for (int mi = 0; mi < 4; mi++)
#pragma unroll
      for (int ni = 0; ni < 4; ni++)
        acc[mi][ni] = __builtin_amdgcn_mfma_f32_16x16x32_bf16(
            af[mi], bfr[ni], acc[mi][ni], 0, 0, 0);
    __syncthreads();
  }

  // epilogue: relu^2 -> bf16 act[(e*CAP + slot)][col]
#pragma unroll
  for (int mi = 0; mi < 4; mi++) {
#pragma unroll
    for (int reg = 0; reg < 4; reg++) {
      int rowt = mt * BM + wm + mi * 16 + qd * 4 + reg;
      if (rowt < n_e) {
#pragma unroll
        for (int ni = 0; ni < 4; ni++) {
          float v = acc[mi][ni][reg];
          v = v > 0.f ? v * v : 0.f;
          int col = nt * BN + wn + ni * 16 + m16;
          act[(e * CAP + rowt) * WW + col] = __float2bfloat16(v);
        }
      }
    }
  }
}

// ---------------- grouped GEMM2: y = act @ W2_e, weighted atomic scatter ----------------
__global__ __launch_bounds__(256) void gemm2_kernel(
    const __hip_bfloat16* __restrict__ act, const __hip_bfloat16* __restrict__ w2t,
    const int* __restrict__ counts, const int* __restrict__ idx,
    const float* __restrict__ aw, float* __restrict__ out)
{
  __shared__ short As[BM * BK];
  __shared__ short Bs[BN * BK];
  int b = blockIdx.x;
  int e = b / (MT * NT);
  int rem = b % (MT * NT);
  int mt = rem / NT, nt = rem % NT;
  int n_e = counts[e];
  if (mt * BM >= n_e) return;

  int tid = threadIdx.x;
  int lane = tid & 63;
  int wave = __builtin_amdgcn_readfirstlane(tid >> 6);
  int wm = (wave >> 1) * 64, wn = (wave & 1) * 64;
  int m16 = lane & 15, qd = lane >> 4;

  const __hip_bfloat16* gA[2];
  const __hip_bfloat16* gB[2];
#pragma unroll
  for (int i = 0; i < 2; i++) {
    int sg = i * 256 + tid;
    int r = sg >> 2;
    int q = (sg & 3) ^ ((r >> 1) & 3);
    gA[i] = act + (e * CAP + mt * BM + r) * WW + q * 8;   // rows >= n_e: garbage, row-isolated
    gB[i] = w2t + (e * DD + nt * BN + r) * WW + q * 8;
  }
  short* ldsA0 = As + (wave * 64) * 8;
  short* ldsA1 = As + (256 + wave * 64) * 8;
  short* ldsB0 = Bs + (wave * 64) * 8;
  short* ldsB1 = Bs + (256 + wave * 64) * 8;

  int aoff[4], boff[4];
#pragma unroll
  for (int i = 0; i < 4; i++) {
    int ra = wm + i * 16 + m16;
    aoff[i] = (ra * 4 + (qd ^ ((ra >> 1) & 3))) * 8;
    int rb = wn + i * 16 + m16;
    boff[i] = (rb * 4 + (qd ^ ((rb >> 1) & 3))) * 8;
  }

  f32x4 zero = {0.f, 0.f, 0.f, 0.f};
  f32x4 acc[4][4];
#pragma unroll
  for (int mi = 0; mi < 4; mi++)
#pragma unroll
    for (int ni = 0; ni < 4; ni++) acc[mi][ni] = zero;

  for (int k0 = 0; k0 < WW; k0 += BK) {
    gload_lds16(gA[0] + k0, ldsA0);
    gload_lds16(gA[1] + k0, ldsA1);
    gload_lds16(gB[0] + k0, ldsB0);
    gload_lds16(gB[1] + k0, ldsB1);
    __syncthreads();
    bf16x8 af[4], bfr[4];
#pragma unroll
    for (int i = 0; i < 4; i++) af[i] = *(const bf16x8*)(As + aoff[i]);
#pragma unroll
    for (int i = 0; i < 4; i++) bfr[i] = *(const bf16x8*)(Bs + boff[i]);
#pragma unroll
    for (int mi = 0; mi < 4; mi++)
#pragma unroll
      for (int ni = 0; ni < 4; ni++)
        acc[mi][ni] = __builtin_amdgcn_mfma_f32_16x16x32_bf16(
            af[mi], bfr[ni], acc[mi][ni], 0, 0, 0);
    __syncthreads();
  }

  // epilogue: out[tok][col] += w * y
#pragma unroll
  for (int mi = 0; mi < 4; mi++) {
#pragma unroll
    for (int reg = 0; reg < 4; reg++) {
      int slot = mt * BM + wm + mi * 16 + qd * 4 + reg;
      if (slot < n_e) {
        int tok = idx[e * CAP + slot];
        float wv = aw[e * CAP + slot];
#pragma unroll
        for (int ni = 0; ni < 4; ni++) {
          int col = nt * BN + wn + ni * 16 + m16;
          atomicAdd(out + tok * DD + col, acc[mi][ni][reg] * wv);
        }
      }
    }
  }
}

extern "C" void kernel_launch(void* const* d_in, const int* in_sizes, int n_in,
                              void* d_out, int out_size, void* d_ws, size_t ws_size,
                              hipStream_t stream)
{
  const float* x  = (const float*)d_in[0];
  const float* rw = (const float*)d_in[1];
  const float* w1 = (const float*)d_in[2];
  const float* w2 = (const float*)d_in[3];
  float* out = (float*)d_out;

  char* ws = (char*)d_ws;
  __hip_bfloat16* xb  = (__hip_bfloat16*)ws;  ws += (size_t)T_TOKENS * DD * 2;
  __hip_bfloat16* w1t = (__hip_bfloat16*)ws;  ws += (size_t)EE * WW * DD * 2;
  __hip_bfloat16* w2t = (__hip_bfloat16*)ws;  ws += (size_t)EE * DD * WW * 2;
  __hip_bfloat16* act = (__hip_bfloat16*)ws;  ws += (size_t)EE * CAP * WW * 2;
  int*   counts = (int*)ws;                   ws += 256;
  int*   idx    = (int*)ws;                   ws += (size_t)EE * CAP * 4;
  float* aw     = (float*)ws;                 ws += (size_t)EE * CAP * 4;

  hipMemsetAsync(counts, 0, 256, stream);
  hipMemsetAsync(d_out, 0, (size_t)out_size * 4, stream);

  dim3 tb(32, 8);
  // w1 [D, E*W] -> w1t [E*W, D]   (full transpose)
  transpose_cvt<<<dim3(DD / 32, (EE * WW) / 32, 1), tb, 0, stream>>>(
      w1, w1t, EE * WW, DD, 0, 0);
  // w2 [E*W, D] -> w2t [E][D, W]  (per-expert transpose)
  transpose_cvt<<<dim3(WW / 32, DD / 32, EE), tb, 0, stream>>>(
      w2, w2t, DD, WW, (long)WW * DD, (long)DD * WW);

  router_kernel<<<T_TOKENS / 4, 256, 0, stream>>>(x, rw, xb, counts, idx, aw);
  gemm1_kernel<<<EE * MT * NT, 256, 0, stream>>>(xb, w1t, counts, idx, act);
  gemm2_kernel<<<EE * MT * NT, 256, 0, stream>>>(act, w2t, counts, idx, aw, out);
}

// Round 2
// 228.190 us; speedup vs baseline: 1.3647x; 1.3647x over previous
//
#include <hip/hip_runtime.h>
#include <hip/hip_bf16.h>

// MoE MLP (top-2 of 8 experts), T=4096 tokens, D=1024, W=1024.
// Pipeline: [transpose+cvt weights] -> [router fp32, NO atomics] -> [build_lists,
//           LDS-atomic single block] -> [grouped GEMM1 + relu^2] -> [GEMM2 + scatter]
// R2: removed the 8192 same-cache-line global atomicAdds from router (was 104us
// of L2-atomic convoy, VALUBusy 3%); list building moved to a 1-block kernel
// using LDS atomics (8 banks parallel).

#define T_TOKENS 4096
#define DD 1024
#define EE 8
#define WW 1024
#define CAP 2048          // per-expert capacity (expected ~1024 +- ~100)
#define BM 128
#define BN 128
#define BK 32
#define MT (CAP / BM)     // 16 m-tiles max per expert
#define NT 8              // 1024/128 n-tiles

typedef short bf16x8 __attribute__((ext_vector_type(8)));
typedef float f32x4 __attribute__((ext_vector_type(4)));

__device__ __forceinline__ void gload_lds16(const void* g, void* l) {
  __builtin_amdgcn_global_load_lds((__attribute__((address_space(1))) void*)(g),
                                   (__attribute__((address_space(3))) void*)(l),
                                   16, 0, 0);
}

// ---------------- transpose + fp32->bf16 convert ----------------
__global__ __launch_bounds__(256) void transpose_cvt(
    const float* __restrict__ src, __hip_bfloat16* __restrict__ dst,
    int src_ld, int dst_ld, long src_blk, long dst_blk)
{
  __shared__ float tile[32][33];
  const float* s = src + (long)blockIdx.z * src_blk;
  __hip_bfloat16* d = dst + (long)blockIdx.z * dst_blk;
  int tx = threadIdx.x, ty = threadIdx.y;
  int c0 = blockIdx.x * 32;   // dst col tile
  int r0 = blockIdx.y * 32;   // dst row tile
#pragma unroll
  for (int i = 0; i < 4; i++)
    tile[ty + 8 * i][tx] = s[(long)(c0 + ty + 8 * i) * src_ld + r0 + tx];
  __syncthreads();
#pragma unroll
  for (int i = 0; i < 4; i++)
    d[(long)(r0 + ty + 8 * i) * dst_ld + c0 + tx] =
        __float2bfloat16(tile[tx][ty + 8 * i]);
}

// ---------------- router: fp32 logits, sigmoid, top-2, NO atomics ----------------
__global__ __launch_bounds__(256) void router_kernel(
    const float* __restrict__ x, const float* __restrict__ rw,
    __hip_bfloat16* __restrict__ xb, int* __restrict__ sel,
    float* __restrict__ wpair)
{
  int lane = threadIdx.x & 63;
  int wave = threadIdx.x >> 6;
  int t = blockIdx.x * 4 + wave;   // one wave per token
  const float* xrow = x + (size_t)t * DD;
  float acc[EE];
#pragma unroll
  for (int e = 0; e < EE; e++) acc[e] = 0.f;
#pragma unroll
  for (int i = 0; i < DD / 64; i++) {
    int d = lane + i * 64;
    float xv = xrow[d];
    xb[t * DD + d] = __float2bfloat16(xv);   // fused x -> bf16
#pragma unroll
    for (int e = 0; e < EE; e++) acc[e] += xv * rw[e * DD + d];
  }
#pragma unroll
  for (int e = 0; e < EE; e++) {
#pragma unroll
    for (int off = 32; off > 0; off >>= 1)
      acc[e] += __shfl_down(acc[e], off, 64);
  }
  if (lane == 0) {
    float p[EE];
#pragma unroll
    for (int e = 0; e < EE; e++) p[e] = 1.f / (1.f + expf(-acc[e]));
    // top-2, ties -> lowest index (matches jax.lax.top_k stable ordering)
    int e0 = 0; float b0 = p[0];
    for (int e = 1; e < EE; e++) if (p[e] > b0) { b0 = p[e]; e0 = e; }
    int e1 = -1; float b1 = -1.f;
    for (int e = 0; e < EE; e++) {
      if (e == e0) continue;
      if (p[e] > b1) { b1 = p[e]; e1 = e; }
    }
    float s = b0 + b1 + 1e-20f;
    sel[t] = e0 | (e1 << 8);
    wpair[2 * t]     = b0 / s;
    wpair[2 * t + 1] = b1 / s;
  }
}

// ---------------- build per-expert token lists (1 block, LDS atomics) ----------------
__global__ __launch_bounds__(1024) void build_lists(
    const int* __restrict__ sel, const float* __restrict__ wpair,
    int* __restrict__ counts, int* __restrict__ idx, float* __restrict__ aw)
{
  __shared__ int lcnt[EE];
  int tid = threadIdx.x;
  if (tid < EE) lcnt[tid] = 0;
  __syncthreads();
#pragma unroll
  for (int j = 0; j < T_TOKENS / 1024; j++) {
    int t = j * 1024 + tid;
    int s = sel[t];
    int e0 = s & 0xff, e1 = (s >> 8) & 0xff;
    float w0 = wpair[2 * t], w1 = wpair[2 * t + 1];
    int s0 = atomicAdd(&lcnt[e0], 1);
    idx[e0 * CAP + s0] = t;  aw[e0 * CAP + s0] = w0;
    int s1 = atomicAdd(&lcnt[e1], 1);
    idx[e1 * CAP + s1] = t;  aw[e1 * CAP + s1] = w1;
  }
  __syncthreads();
  if (tid < EE) counts[tid] = lcnt[tid];
}

// ---------------- grouped GEMM1: h = gather(xb) @ W1_e, act = relu(h)^2 ----------------
__global__ __launch_bounds__(256) void gemm1_kernel(
    const __hip_bfloat16* __restrict__ xb, const __hip_bfloat16* __restrict__ w1t,
    const int* __restrict__ counts, const int* __restrict__ idx,
    __hip_bfloat16* __restrict__ act)
{
  __shared__ short As[BM * BK];
  __shared__ short Bs[BN * BK];
  int b = blockIdx.x;
  int e = b / (MT * NT);
  int rem = b % (MT * NT);
  int mt = rem / NT, nt = rem % NT;
  int n_e = counts[e];
  if (mt * BM >= n_e) return;

  int tid = threadIdx.x;
  int lane = tid & 63;
  int wave = __builtin_amdgcn_readfirstlane(tid >> 6);
  int wm = (wave >> 1) * 64, wn = (wave & 1) * 64;
  int m16 = lane & 15, qd = lane >> 4;

  // staging: 2 granules (16B) each of A and B per thread; LDS granule sg = i*256+tid
  const __hip_bfloat16* gA[2];
  const __hip_bfloat16* gB[2];
#pragma unroll
  for (int i = 0; i < 2; i++) {
    int sg = i * 256 + tid;
    int r = sg >> 2;
    int q = (sg & 3) ^ ((r >> 1) & 3);        // un-swizzle: logical k-granule
    int rowA = mt * BM + r;
    int slot = rowA < n_e ? rowA : n_e - 1;   // clamp tail rows to valid slot
    int tok = idx[e * CAP + slot];
    gA[i] = xb + tok * DD + q * 8;
    gB[i] = w1t + (e * WW + nt * BN + r) * DD + q * 8;
  }
  short* ldsA0 = As + (wave * 64) * 8;
  short* ldsA1 = As + (256 + wave * 64) * 8;
  short* ldsB0 = Bs + (wave * 64) * 8;
  short* ldsB1 = Bs + (256 + wave * 64) * 8;

  int aoff[4], boff[4];
#pragma unroll
  for (int i = 0; i < 4; i++) {
    int ra = wm + i * 16 + m16;
    aoff[i] = (ra * 4 + (qd ^ ((ra >> 1) & 3))) * 8;
    int rb = wn + i * 16 + m16;
    boff[i] = (rb * 4 + (qd ^ ((rb >> 1) & 3))) * 8;
  }

  f32x4 zero = {0.f, 0.f, 0.f, 0.f};
  f32x4 acc[4][4];
#pragma unroll
  for (int mi = 0; mi < 4; mi++)
#pragma unroll
    for (int ni = 0; ni < 4; ni++) acc[mi][ni] = zero;

  for (int k0 = 0; k0 < DD; k0 += BK) {
    gload_lds16(gA[0] + k0, ldsA0);
    gload_lds16(gA[1] + k0, ldsA1);
    gload_lds16(gB[0] + k0, ldsB0);
    gload_lds16(gB[1] + k0, ldsB1);
    __syncthreads();
    bf16x8 af[4], bfr[4];
#pragma unroll
    for (int i = 0; i < 4; i++) af[i] = *(const bf16x8*)(As + aoff[i]);
#pragma unroll
    for (int i = 0; i < 4; i++) bfr[i] = *(const bf16x8*)(Bs + boff[i]);
#pragma unroll
    for (int mi = 0; mi < 4; mi++)
#pragma unroll
      for (int ni = 0; ni < 4; ni++)
        acc[mi][ni] = __builtin_amdgcn_mfma_f32_16x16x32_bf16(
            af[mi], bfr[ni], acc[mi][ni], 0, 0, 0);
    __syncthreads();
  }

  // epilogue: relu^2 -> bf16 act[(e*CAP + slot)][col]
#pragma unroll
  for (int mi = 0; mi < 4; mi++) {
#pragma unroll
    for (int reg = 0; reg < 4; reg++) {
      int rowt = mt * BM + wm + mi * 16 + qd * 4 + reg;
      if (rowt < n_e) {
#pragma unroll
        for (int ni = 0; ni < 4; ni++) {
          float v = acc[mi][ni][reg];
          v = v > 0.f ? v * v : 0.f;
          int col = nt * BN + wn + ni * 16 + m16;
          act[(e * CAP + rowt) * WW + col] = __float2bfloat16(v);
        }
      }
    }
  }
}

// ---------------- grouped GEMM2: y = act @ W2_e, weighted atomic scatter ----------------
__global__ __launch_bounds__(256) void gemm2_kernel(
    const __hip_bfloat16* __restrict__ act, const __hip_bfloat16* __restrict__ w2t,
    const int* __restrict__ counts, const int* __restrict__ idx,
    const float* __restrict__ aw, float* __restrict__ out)
{
  __shared__ short As[BM * BK];
  __shared__ short Bs[BN * BK];
  int b = blockIdx.x;
  int e = b / (MT * NT);
  int rem = b % (MT * NT);
  int mt = rem / NT, nt = rem % NT;
  int n_e = counts[e];
  if (mt * BM >= n_e) return;

  int tid = threadIdx.x;
  int lane = tid & 63;
  int wave = __builtin_amdgcn_readfirstlane(tid >> 6);
  int wm = (wave >> 1) * 64, wn = (wave & 1) * 64;
  int m16 = lane & 15, qd = lane >> 4;

  const __hip_bfloat16* gA[2];
  const __hip_bfloat16* gB[2];
#pragma unroll
  for (int i = 0; i < 2; i++) {
    int sg = i * 256 + tid;
    int r = sg >> 2;
    int q = (sg & 3) ^ ((r >> 1) & 3);
    gA[i] = act + (e * CAP + mt * BM + r) * WW + q * 8;   // rows >= n_e: garbage, row-isolated
    gB[i] = w2t + (e * DD + nt * BN + r) * WW + q * 8;
  }
  short* ldsA0 = As + (wave * 64) * 8;
  short* ldsA1 = As + (256 + wave * 64) * 8;
  short* ldsB0 = Bs + (wave * 64) * 8;
  short* ldsB1 = Bs + (256 + wave * 64) * 8;

  int aoff[4], boff[4];
#pragma unroll
  for (int i = 0; i < 4; i++) {
    int ra = wm + i * 16 + m16;
    aoff[i] = (ra * 4 + (qd ^ ((ra >> 1) & 3))) * 8;
    int rb = wn + i * 16 + m16;
    boff[i] = (rb * 4 + (qd ^ ((rb >> 1) & 3))) * 8;
  }

  f32x4 zero = {0.f, 0.f, 0.f, 0.f};
  f32x4 acc[4][4];
#pragma unroll
  for (int mi = 0; mi < 4; mi++)
#pragma unroll
    for (int ni = 0; ni < 4; ni++) acc[mi][ni] = zero;

  for (int k0 = 0; k0 < WW; k0 += BK) {
    gload_lds16(gA[0] + k0, ldsA0);
    gload_lds16(gA[1] + k0, ldsA1);
    gload_lds16(gB[0] + k0, ldsB0);
    gload_lds16(gB[1] + k0, ldsB1);
    __syncthreads();
    bf16x8 af[4], bfr[4];
#pragma unroll
    for (int i = 0; i < 4; i++) af[i] = *(const bf16x8*)(As + aoff[i]);
#pragma unroll
    for (int i = 0; i < 4; i++) bfr[i] = *(const bf16x8*)(Bs + boff[i]);
#pragma unroll
    for (int mi = 0; mi < 4; mi++)
#pragma unroll
      for (int ni = 0; ni < 4; ni++)
        acc[mi][ni] = __builtin_amdgcn_mfma_f32_16x16x32_bf16(
            af[mi], bfr[ni], acc[mi][ni], 0, 0, 0);
    __syncthreads();
  }

  // epilogue: out[tok][col] += w * y
#pragma unroll
  for (int mi = 0; mi < 4; mi++) {
#pragma unroll
    for (int reg = 0; reg < 4; reg++) {
      int slot = mt * BM + wm + mi * 16 + qd * 4 + reg;
      if (slot < n_e) {
        int tok = idx[e * CAP + slot];
        float wv = aw[e * CAP + slot];
#pragma unroll
        for (int ni = 0; ni < 4; ni++) {
          int col = nt * BN + wn + ni * 16 + m16;
          atomicAdd(out + tok * DD + col, acc[mi][ni][reg] * wv);
        }
      }
    }
  }
}

extern "C" void kernel_launch(void* const* d_in, const int* in_sizes, int n_in,
                              void* d_out, int out_size, void* d_ws, size_t ws_size,
                              hipStream_t stream)
{
  const float* x  = (const float*)d_in[0];
  const float* rw = (const float*)d_in[1];
  const float* w1 = (const float*)d_in[2];
  const float* w2 = (const float*)d_in[3];
  float* out = (float*)d_out;

  char* ws = (char*)d_ws;
  __hip_bfloat16* xb  = (__hip_bfloat16*)ws;  ws += (size_t)T_TOKENS * DD * 2;
  __hip_bfloat16* w1t = (__hip_bfloat16*)ws;  ws += (size_t)EE * WW * DD * 2;
  __hip_bfloat16* w2t = (__hip_bfloat16*)ws;  ws += (size_t)EE * DD * WW * 2;
  __hip_bfloat16* act = (__hip_bfloat16*)ws;  ws += (size_t)EE * CAP * WW * 2;
  int*   counts = (int*)ws;                   ws += 256;
  int*   idx    = (int*)ws;                   ws += (size_t)EE * CAP * 4;
  float* aw     = (float*)ws;                 ws += (size_t)EE * CAP * 4;
  int*   sel    = (int*)ws;                   ws += (size_t)T_TOKENS * 4;
  float* wpair  = (float*)ws;                 ws += (size_t)T_TOKENS * 8;

  hipMemsetAsync(d_out, 0, (size_t)out_size * 4, stream);

  dim3 tb(32, 8);
  // w1 [D, E*W] -> w1t [E*W, D]   (full transpose)
  transpose_cvt<<<dim3(DD / 32, (EE * WW) / 32, 1), tb, 0, stream>>>(
      w1, w1t, EE * WW, DD, 0, 0);
  // w2 [E*W, D] -> w2t [E][D, W]  (per-expert transpose)
  transpose_cvt<<<dim3(WW / 32, DD / 32, EE), tb, 0, stream>>>(
      w2, w2t, DD, WW, (long)WW * DD, (long)DD * WW);

  router_kernel<<<T_TOKENS / 4, 256, 0, stream>>>(x, rw, xb, sel, wpair);
  build_lists<<<1, 1024, 0, stream>>>(sel, wpair, counts, idx, aw);
  gemm1_kernel<<<EE * MT * NT, 256, 0, stream>>>(xb, w1t, counts, idx, act);
  gemm2_kernel<<<EE * MT * NT, 256, 0, stream>>>(act, w2t, counts, idx, aw, out);
}

// Round 3
// 220.432 us; speedup vs baseline: 1.4128x; 1.0352x over previous
//
#include <hip/hip_runtime.h>
#include <hip/hip_bf16.h>

// MoE MLP (top-2 of 8 experts), T=4096 tokens, D=1024, W=1024.
// R3: (1) gemm2 atomics removed -> raw bf16 y per slot + combine kernel
//     (2) GEMM tiles 128x64 -> 2048 blocks (4 blocks/CU, was 2)
//     (3) transposes vectorized (float4 loads / ushort4 stores)

#define T_TOKENS 4096
#define DD 1024
#define EE 8
#define WW 1024
#define CAP 2048          // per-expert capacity (expected ~1024 +- ~100)
#define BM 128
#define BN 64
#define BK 32
#define MT (CAP / BM)     // 16 m-tiles max per expert
#define NT 16             // 1024/64 n-tiles

typedef short bf16x8 __attribute__((ext_vector_type(8)));
typedef float f32x4 __attribute__((ext_vector_type(4)));

__device__ __forceinline__ void gload_lds16(const void* g, void* l) {
  __builtin_amdgcn_global_load_lds((__attribute__((address_space(1))) void*)(g),
                                   (__attribute__((address_space(3))) void*)(l),
                                   16, 0, 0);
}

__device__ __forceinline__ float bf2f(unsigned short u) {
  union { unsigned int i; float f; } v; v.i = (unsigned int)u << 16; return v.f;
}

// ---------------- transpose + fp32->bf16 convert (64x64 tile, vectorized) ----------------
// dst[r*dst_ld + c] = bf16(src[c*src_ld + r])
__global__ __launch_bounds__(256) void transpose_cvt(
    const float* __restrict__ src, __hip_bfloat16* __restrict__ dst,
    int src_ld, int dst_ld, long src_blk, long dst_blk)
{
  __shared__ float tile[64][65];
  const float* s = src + (long)blockIdx.z * src_blk;
  __hip_bfloat16* d = dst + (long)blockIdx.z * dst_blk;
  int tx = threadIdx.x;       // 0..15
  int ty = threadIdx.y;       // 0..15
  int c0 = blockIdx.x * 64;   // dst col tile = src row tile
  int r0 = blockIdx.y * 64;   // dst row tile = src col tile
#pragma unroll
  for (int i = 0; i < 4; i++) {
    int sr = ty + 16 * i;
    f32x4 v = *(const f32x4*)(s + (long)(c0 + sr) * src_ld + r0 + tx * 4);
    tile[sr][tx * 4 + 0] = v[0];
    tile[sr][tx * 4 + 1] = v[1];
    tile[sr][tx * 4 + 2] = v[2];
    tile[sr][tx * 4 + 3] = v[3];
  }
  __syncthreads();
#pragma unroll
  for (int i = 0; i < 4; i++) {
    int dr = ty + 16 * i;
    union { __hip_bfloat16 hb[4]; ushort4 u4; } pk;
#pragma unroll
    for (int j = 0; j < 4; j++)
      pk.hb[j] = __float2bfloat16(tile[tx * 4 + j][dr]);
    *(ushort4*)((unsigned short*)d + (long)(r0 + dr) * dst_ld + c0 + tx * 4) = pk.u4;
  }
}

// ---------------- router: fp32 logits, sigmoid, top-2, NO atomics ----------------
__global__ __launch_bounds__(256) void router_kernel(
    const float* __restrict__ x, const float* __restrict__ rw,
    __hip_bfloat16* __restrict__ xb, int* __restrict__ sel,
    float* __restrict__ wpair)
{
  int lane = threadIdx.x & 63;
  int wave = threadIdx.x >> 6;
  int t = blockIdx.x * 4 + wave;   // one wave per token
  const float* xrow = x + (size_t)t * DD;
  float acc[EE];
#pragma unroll
  for (int e = 0; e < EE; e++) acc[e] = 0.f;
#pragma unroll
  for (int i = 0; i < DD / 64; i++) {
    int d = lane + i * 64;
    float xv = xrow[d];
    xb[t * DD + d] = __float2bfloat16(xv);   // fused x -> bf16
#pragma unroll
    for (int e = 0; e < EE; e++) acc[e] += xv * rw[e * DD + d];
  }
#pragma unroll
  for (int e = 0; e < EE; e++) {
#pragma unroll
    for (int off = 32; off > 0; off >>= 1)
      acc[e] += __shfl_down(acc[e], off, 64);
  }
  if (lane == 0) {
    float p[EE];
#pragma unroll
    for (int e = 0; e < EE; e++) p[e] = 1.f / (1.f + expf(-acc[e]));
    // top-2, ties -> lowest index (matches jax.lax.top_k stable ordering)
    int e0 = 0; float b0 = p[0];
    for (int e = 1; e < EE; e++) if (p[e] > b0) { b0 = p[e]; e0 = e; }
    int e1 = -1; float b1 = -1.f;
    for (int e = 0; e < EE; e++) {
      if (e == e0) continue;
      if (p[e] > b1) { b1 = p[e]; e1 = e; }
    }
    float s = b0 + b1 + 1e-20f;
    sel[t] = e0 | (e1 << 8);
    wpair[2 * t]     = b0 / s;
    wpair[2 * t + 1] = b1 / s;
  }
}

// ---------------- build per-expert token lists (1 block, LDS atomics) ----------------
__global__ __launch_bounds__(1024) void build_lists(
    const int* __restrict__ sel, int* __restrict__ counts,
    int* __restrict__ idx, int* __restrict__ tslot)
{
  __shared__ int lcnt[EE];
  int tid = threadIdx.x;
  if (tid < EE) lcnt[tid] = 0;
  __syncthreads();
#pragma unroll
  for (int j = 0; j < T_TOKENS / 1024; j++) {
    int t = j * 1024 + tid;
    int s = sel[t];
    int e0 = s & 0xff, e1 = (s >> 8) & 0xff;
    int s0 = atomicAdd(&lcnt[e0], 1);
    idx[e0 * CAP + s0] = t;
    int s1 = atomicAdd(&lcnt[e1], 1);
    idx[e1 * CAP + s1] = t;
    tslot[2 * t]     = e0 * CAP + s0;
    tslot[2 * t + 1] = e1 * CAP + s1;
  }
  __syncthreads();
  if (tid < EE) counts[tid] = lcnt[tid];
}

// ---------------- grouped GEMM1: h = gather(xb) @ W1_e, act = relu(h)^2 ----------------
__global__ __launch_bounds__(256) void gemm1_kernel(
    const __hip_bfloat16* __restrict__ xb, const __hip_bfloat16* __restrict__ w1t,
    const int* __restrict__ counts, const int* __restrict__ idx,
    __hip_bfloat16* __restrict__ act)
{
  __shared__ short As[BM * BK];   // 8 KB
  __shared__ short Bs[BN * BK];   // 4 KB
  int b = blockIdx.x;
  int e = b / (MT * NT);
  int rem = b % (MT * NT);
  int mt = rem / NT, nt = rem % NT;
  int n_e = counts[e];
  if (mt * BM >= n_e) return;

  int tid = threadIdx.x;
  int lane = tid & 63;
  int wave = __builtin_amdgcn_readfirstlane(tid >> 6);
  int wm = (wave >> 1) * 64, wn = (wave & 1) * 32;
  int m16 = lane & 15, qd = lane >> 4;

  // staging: A = 2 granules/thread, B = 1 granule/thread (16B each)
  const __hip_bfloat16* gA[2];
  const __hip_bfloat16* gB;
#pragma unroll
  for (int i = 0; i < 2; i++) {
    int sg = i * 256 + tid;
    int r = sg >> 2;
    int q = (sg & 3) ^ ((r >> 1) & 3);        // un-swizzle: logical k-granule
    int rowA = mt * BM + r;
    int slot = rowA < n_e ? rowA : n_e - 1;   // clamp tail rows to valid slot
    int tok = idx[e * CAP + slot];
    gA[i] = xb + tok * DD + q * 8;
  }
  {
    int r = tid >> 2;
    int q = (tid & 3) ^ ((r >> 1) & 3);
    gB = w1t + (e * WW + nt * BN + r) * DD + q * 8;
  }
  short* ldsA0 = As + (wave * 64) * 8;
  short* ldsA1 = As + (256 + wave * 64) * 8;
  short* ldsB  = Bs + (wave * 64) * 8;

  int aoff[4], boff[2];
#pragma unroll
  for (int i = 0; i < 4; i++) {
    int ra = wm + i * 16 + m16;
    aoff[i] = (ra * 4 + (qd ^ ((ra >> 1) & 3))) * 8;
  }
#pragma unroll
  for (int i = 0; i < 2; i++) {
    int rb = wn + i * 16 + m16;
    boff[i] = (rb * 4 + (qd ^ ((rb >> 1) & 3))) * 8;
  }

  f32x4 zero = {0.f, 0.f, 0.f, 0.f};
  f32x4 acc[4][2];
#pragma unroll
  for (int mi = 0; mi < 4; mi++)
#pragma unroll
    for (int ni = 0; ni < 2; ni++) acc[mi][ni] = zero;

  for (int k0 = 0; k0 < DD; k0 += BK) {
    gload_lds16(gA[0] + k0, ldsA0);
    gload_lds16(gA[1] + k0, ldsA1);
    gload_lds16(gB + k0, ldsB);
    __syncthreads();
    bf16x8 af[4], bfr[2];
#pragma unroll
    for (int i = 0; i < 4; i++) af[i] = *(const bf16x8*)(As + aoff[i]);
#pragma unroll
    for (int i = 0; i < 2; i++) bfr[i] = *(const bf16x8*)(Bs + boff[i]);
#pragma unroll
    for (int mi = 0; mi < 4; mi++)
#pragma unroll
      for (int ni = 0; ni < 2; ni++)
        acc[mi][ni] = __builtin_amdgcn_mfma_f32_16x16x32_bf16(
            af[mi], bfr[ni], acc[mi][ni], 0, 0, 0);
    __syncthreads();
  }

  // epilogue: relu^2 -> bf16 act[(e*CAP + slot)][col]
#pragma unroll
  for (int mi = 0; mi < 4; mi++) {
#pragma unroll
    for (int reg = 0; reg < 4; reg++) {
      int rowt = mt * BM + wm + mi * 16 + qd * 4 + reg;
      if (rowt < n_e) {
#pragma unroll
        for (int ni = 0; ni < 2; ni++) {
          float v = acc[mi][ni][reg];
          v = v > 0.f ? v * v : 0.f;
          int col = nt * BN + wn + ni * 16 + m16;
          act[(e * CAP + rowt) * WW + col] = __float2bfloat16(v);
        }
      }
    }
  }
}

// ---------------- grouped GEMM2: y = act @ W2_e (raw bf16 y, no atomics) ----------------
__global__ __launch_bounds__(256) void gemm2_kernel(
    const __hip_bfloat16* __restrict__ act, const __hip_bfloat16* __restrict__ w2t,
    const int* __restrict__ counts, __hip_bfloat16* __restrict__ y)
{
  __shared__ short As[BM * BK];
  __shared__ short Bs[BN * BK];
  int b = blockIdx.x;
  int e = b / (MT * NT);
  int rem = b % (MT * NT);
  int mt = rem / NT, nt = rem % NT;
  int n_e = counts[e];
  if (mt * BM >= n_e) return;

  int tid = threadIdx.x;
  int lane = tid & 63;
  int wave = __builtin_amdgcn_readfirstlane(tid >> 6);
  int wm = (wave >> 1) * 64, wn = (wave & 1) * 32;
  int m16 = lane & 15, qd = lane >> 4;

  const __hip_bfloat16* gA[2];
  const __hip_bfloat16* gB;
#pragma unroll
  for (int i = 0; i < 2; i++) {
    int sg = i * 256 + tid;
    int r = sg >> 2;
    int q = (sg & 3) ^ ((r >> 1) & 3);
    gA[i] = act + (e * CAP + mt * BM + r) * WW + q * 8;  // rows >= n_e: garbage, row-isolated
  }
  {
    int r = tid >> 2;
    int q = (tid & 3) ^ ((r >> 1) & 3);
    gB = w2t + (e * DD + nt * BN + r) * WW + q * 8;
  }
  short* ldsA0 = As + (wave * 64) * 8;
  short* ldsA1 = As + (256 + wave * 64) * 8;
  short* ldsB  = Bs + (wave * 64) * 8;

  int aoff[4], boff[2];
#pragma unroll
  for (int i = 0; i < 4; i++) {
    int ra = wm + i * 16 + m16;
    aoff[i] = (ra * 4 + (qd ^ ((ra >> 1) & 3))) * 8;
  }
#pragma unroll
  for (int i = 0; i < 2; i++) {
    int rb = wn + i * 16 + m16;
    boff[i] = (rb * 4 + (qd ^ ((rb >> 1) & 3))) * 8;
  }

  f32x4 zero = {0.f, 0.f, 0.f, 0.f};
  f32x4 acc[4][2];
#pragma unroll
  for (int mi = 0; mi < 4; mi++)
#pragma unroll
    for (int ni = 0; ni < 2; ni++) acc[mi][ni] = zero;

  for (int k0 = 0; k0 < WW; k0 += BK) {
    gload_lds16(gA[0] + k0, ldsA0);
    gload_lds16(gA[1] + k0, ldsA1);
    gload_lds16(gB + k0, ldsB);
    __syncthreads();
    bf16x8 af[4], bfr[2];
#pragma unroll
    for (int i = 0; i < 4; i++) af[i] = *(const bf16x8*)(As + aoff[i]);
#pragma unroll
    for (int i = 0; i < 2; i++) bfr[i] = *(const bf16x8*)(Bs + boff[i]);
#pragma unroll
    for (int mi = 0; mi < 4; mi++)
#pragma unroll
      for (int ni = 0; ni < 2; ni++)
        acc[mi][ni] = __builtin_amdgcn_mfma_f32_16x16x32_bf16(
            af[mi], bfr[ni], acc[mi][ni], 0, 0, 0);
    __syncthreads();
  }

  // epilogue: raw y (weights applied in combine)
#pragma unroll
  for (int mi = 0; mi < 4; mi++) {
#pragma unroll
    for (int reg = 0; reg < 4; reg++) {
      int slot = mt * BM + wm + mi * 16 + qd * 4 + reg;
      if (slot < n_e) {
#pragma unroll
        for (int ni = 0; ni < 2; ni++) {
          int col = nt * BN + wn + ni * 16 + m16;
          y[(e * CAP + slot) * DD + col] = __float2bfloat16(acc[mi][ni][reg]);
        }
      }
    }
  }
}

// ---------------- combine: out[t] = w0*y[slot0] + w1*y[slot1] ----------------
__global__ __launch_bounds__(256) void combine_kernel(
    const __hip_bfloat16* __restrict__ y, const int* __restrict__ tslot,
    const float* __restrict__ wpair, float* __restrict__ out)
{
  int t = blockIdx.x;
  int c = threadIdx.x * 4;
  int s0 = tslot[2 * t], s1 = tslot[2 * t + 1];
  float w0 = wpair[2 * t], w1 = wpair[2 * t + 1];
  const unsigned short* yu = (const unsigned short*)y;
  ushort4 a = *(const ushort4*)(yu + (size_t)s0 * DD + c);
  ushort4 bq = *(const ushort4*)(yu + (size_t)s1 * DD + c);
  f32x4 o;
  o[0] = w0 * bf2f(a.x) + w1 * bf2f(bq.x);
  o[1] = w0 * bf2f(a.y) + w1 * bf2f(bq.y);
  o[2] = w0 * bf2f(a.z) + w1 * bf2f(bq.z);
  o[3] = w0 * bf2f(a.w) + w1 * bf2f(bq.w);
  *(f32x4*)(out + (size_t)t * DD + c) = o;
}

extern "C" void kernel_launch(void* const* d_in, const int* in_sizes, int n_in,
                              void* d_out, int out_size, void* d_ws, size_t ws_size,
                              hipStream_t stream)
{
  const float* x  = (const float*)d_in[0];
  const float* rw = (const float*)d_in[1];
  const float* w1 = (const float*)d_in[2];
  const float* w2 = (const float*)d_in[3];
  float* out = (float*)d_out;

  char* ws = (char*)d_ws;
  __hip_bfloat16* xb  = (__hip_bfloat16*)ws;  ws += (size_t)T_TOKENS * DD * 2;
  __hip_bfloat16* w1t = (__hip_bfloat16*)ws;  ws += (size_t)EE * WW * DD * 2;
  __hip_bfloat16* w2t = (__hip_bfloat16*)ws;  ws += (size_t)EE * DD * WW * 2;
  __hip_bfloat16* act = (__hip_bfloat16*)ws;  ws += (size_t)EE * CAP * WW * 2;
  __hip_bfloat16* y   = (__hip_bfloat16*)ws;  ws += (size_t)EE * CAP * DD * 2;
  int*   counts = (int*)ws;                   ws += 256;
  int*   idx    = (int*)ws;                   ws += (size_t)EE * CAP * 4;
  int*   sel    = (int*)ws;                   ws += (size_t)T_TOKENS * 4;
  int*   tslot  = (int*)ws;                   ws += (size_t)T_TOKENS * 8;
  float* wpair  = (float*)ws;                 ws += (size_t)T_TOKENS * 8;

  dim3 tb(16, 16);
  // w1 [D, E*W] -> w1t [E*W, D]   (full transpose)
  transpose_cvt<<<dim3(DD / 64, (EE * WW) / 64, 1), tb, 0, stream>>>(
      w1, w1t, EE * WW, DD, 0, 0);
  // w2 [E*W, D] -> w2t [E][D, W]  (per-expert transpose)
  transpose_cvt<<<dim3(WW / 64, DD / 64, EE), tb, 0, stream>>>(
      w2, w2t, DD, WW, (long)WW * DD, (long)DD * WW);

  router_kernel<<<T_TOKENS / 4, 256, 0, stream>>>(x, rw, xb, sel, wpair);
  build_lists<<<1, 1024, 0, stream>>>(sel, counts, idx, tslot);
  gemm1_kernel<<<EE * MT * NT, 256, 0, stream>>>(xb, w1t, counts, idx, act);
  gemm2_kernel<<<EE * MT * NT, 256, 0, stream>>>(act, w2t, counts, y);
  combine_kernel<<<T_TOKENS, 256, 0, stream>>>(y, tslot, wpair, out);
}

// Round 5
// 203.138 us; speedup vs baseline: 1.5331x; 1.0851x over previous
//
#include <hip/hip_runtime.h>
#include <hip/hip_bf16.h>

// MoE MLP (top-2 of 8 experts), T=4096 tokens, D=1024, W=1024.
// R5: fix R4's pre_kernel block map (w2 transpose needs 2048 blocks, had 256 ->
//     w2t was mostly poison, out ~= 0). TR_BLOCKS = 2048(w1) + 2048(w2) = 4096.
// R4 ideas retained: XCD-aware tile map (expert = bid&7 -> expert slabs stay in
// one XCD's 4MB L2), fused transpose+router pre-phase, CAP=1536.

#define T_TOKENS 4096
#define DD 1024
#define EE 8
#define WW 1024
#define CAP 1536          // per-expert capacity (expected ~1024 +- ~30)
#define BM 128
#define BN 64
#define BK 32
#define MT (CAP / BM)     // 12 m-tiles max per expert
#define NT 16             // 1024/64 n-tiles

typedef short bf16x8 __attribute__((ext_vector_type(8)));
typedef float f32x4 __attribute__((ext_vector_type(4)));

__device__ __forceinline__ void gload_lds16(const void* g, void* l) {
  __builtin_amdgcn_global_load_lds((__attribute__((address_space(1))) void*)(g),
                                   (__attribute__((address_space(3))) void*)(l),
                                   16, 0, 0);
}

__device__ __forceinline__ float bf2f(unsigned short u) {
  union { unsigned int i; float f; } v; v.i = (unsigned int)u << 16; return v.f;
}

// ---------------- fused pre-phase: weight transposes + router ----------------
// blocks [0,2048): w1 transpose; [2048,4096): w2 transpose; [4096,5120): router.
#define TR_BLOCKS 4096
__global__ __launch_bounds__(256) void pre_kernel(
    const float* __restrict__ w1, const float* __restrict__ w2,
    const float* __restrict__ x, const float* __restrict__ rw,
    __hip_bfloat16* __restrict__ w1t, __hip_bfloat16* __restrict__ w2t,
    __hip_bfloat16* __restrict__ xb, int* __restrict__ sel,
    float* __restrict__ wpair)
{
  __shared__ float tile[64][65];
  int b = blockIdx.x;
  if (b < TR_BLOCKS) {
    // ---- transpose part: dst[r*dst_ld+c] = bf16(src[c*src_ld+r]), 64x64 tile ----
    int bx = b & 15;            // dst col tile (16 tiles of 64 over 1024)
    int by = b >> 4;            // 0..255
    const float* src; __hip_bfloat16* dst;
    long src_ld, dst_ld, c0, r0;
    if (by < 128) {
      // w1 [D=1024, E*W=8192] -> w1t [8192, 1024]
      src = w1; dst = w1t; src_ld = EE * WW; dst_ld = DD;
      c0 = (long)bx * 64;       // dst col = src row, 0..1023
      r0 = (long)by * 64;       // dst row = src col, 0..8191
    } else {
      // w2 [E*W, D] expert slice e: [W=1024, D=1024] -> w2t[e] [D=1024, W=1024]
      int z = by - 128;         // 0..127
      int e = z >> 4;           // expert 0..7
      int yy = z & 15;          // dst row tile within expert, 0..15
      src = w2 + (long)e * WW * DD;
      dst = w2t + (long)e * DD * WW;
      src_ld = DD; dst_ld = WW;
      c0 = (long)bx * 64;       // dst col = src row (W dim)
      r0 = (long)yy * 64;       // dst row = src col (D dim)
    }
    int tx = threadIdx.x & 15, ty = threadIdx.x >> 4;
#pragma unroll
    for (int i = 0; i < 4; i++) {
      int sr = ty + 16 * i;
      f32x4 v = *(const f32x4*)(src + (c0 + sr) * src_ld + r0 + tx * 4);
      tile[sr][tx * 4 + 0] = v[0];
      tile[sr][tx * 4 + 1] = v[1];
      tile[sr][tx * 4 + 2] = v[2];
      tile[sr][tx * 4 + 3] = v[3];
    }
    __syncthreads();
#pragma unroll
    for (int i = 0; i < 4; i++) {
      int dr = ty + 16 * i;
      union { __hip_bfloat16 hb[4]; ushort4 u4; } pk;
#pragma unroll
      for (int j = 0; j < 4; j++)
        pk.hb[j] = __float2bfloat16(tile[tx * 4 + j][dr]);
      *(ushort4*)((unsigned short*)dst + (r0 + dr) * dst_ld + c0 + tx * 4) = pk.u4;
    }
  } else {
    // ---- router part: one wave per token, fp32 logits, top-2, no atomics ----
    int lane = threadIdx.x & 63;
    int wave = threadIdx.x >> 6;
    int t = (b - TR_BLOCKS) * 4 + wave;
    const float* xrow = x + (size_t)t * DD;
    float acc[EE];
#pragma unroll
    for (int e = 0; e < EE; e++) acc[e] = 0.f;
#pragma unroll
    for (int i = 0; i < DD / 64; i++) {
      int d = lane + i * 64;
      float xv = xrow[d];
      xb[t * DD + d] = __float2bfloat16(xv);   // fused x -> bf16
#pragma unroll
      for (int e = 0; e < EE; e++) acc[e] += xv * rw[e * DD + d];
    }
#pragma unroll
    for (int e = 0; e < EE; e++) {
#pragma unroll
      for (int off = 32; off > 0; off >>= 1)
        acc[e] += __shfl_down(acc[e], off, 64);
    }
    if (lane == 0) {
      float p[EE];
#pragma unroll
      for (int e = 0; e < EE; e++) p[e] = 1.f / (1.f + expf(-acc[e]));
      // top-2, ties -> lowest index (matches jax.lax.top_k stable ordering)
      int e0 = 0; float b0 = p[0];
      for (int e = 1; e < EE; e++) if (p[e] > b0) { b0 = p[e]; e0 = e; }
      int e1 = -1; float b1 = -1.f;
      for (int e = 0; e < EE; e++) {
        if (e == e0) continue;
        if (p[e] > b1) { b1 = p[e]; e1 = e; }
      }
      float s = b0 + b1 + 1e-20f;
      sel[t] = e0 | (e1 << 8);
      wpair[2 * t]     = b0 / s;
      wpair[2 * t + 1] = b1 / s;
    }
  }
}

// ---------------- build per-expert token lists (1 block, LDS atomics) ----------------
__global__ __launch_bounds__(1024) void build_lists(
    const int* __restrict__ sel, int* __restrict__ counts,
    int* __restrict__ idx, int* __restrict__ tslot)
{
  __shared__ int lcnt[EE];
  int tid = threadIdx.x;
  if (tid < EE) lcnt[tid] = 0;
  __syncthreads();
#pragma unroll
  for (int j = 0; j < T_TOKENS / 1024; j++) {
    int t = j * 1024 + tid;
    int s = sel[t];
    int e0 = s & 0xff, e1 = (s >> 8) & 0xff;
    int s0 = atomicAdd(&lcnt[e0], 1);
    idx[e0 * CAP + s0] = t;
    int s1 = atomicAdd(&lcnt[e1], 1);
    idx[e1 * CAP + s1] = t;
    tslot[2 * t]     = e0 * CAP + s0;
    tslot[2 * t + 1] = e1 * CAP + s1;
  }
  __syncthreads();
  if (tid < EE) counts[tid] = lcnt[tid];
}

// ---------------- grouped GEMM1: h = gather(xb) @ W1_e, act = relu(h)^2 ----------------
// XCD map: expert = bid & 7 (round-robin dispatch puts expert e on XCD e;
// B slab 2MB + A slab ~2MB stay L2-resident).
__global__ __launch_bounds__(256) void gemm1_kernel(
    const __hip_bfloat16* __restrict__ xb, const __hip_bfloat16* __restrict__ w1t,
    const int* __restrict__ counts, const int* __restrict__ idx,
    __hip_bfloat16* __restrict__ act)
{
  __shared__ short As[BM * BK];   // 8 KB
  __shared__ short Bs[BN * BK];   // 4 KB
  int bid = blockIdx.x;
  int e = bid & 7;
  int i = bid >> 3;               // 0..MT*NT-1, nt fastest
  int mt = i >> 4, nt = i & 15;
  int n_e = counts[e];
  if (mt * BM >= n_e) return;

  int tid = threadIdx.x;
  int lane = tid & 63;
  int wave = __builtin_amdgcn_readfirstlane(tid >> 6);
  int wm = (wave >> 1) * 64, wn = (wave & 1) * 32;
  int m16 = lane & 15, qd = lane >> 4;

  // staging: A = 2 granules/thread, B = 1 granule/thread (16B each)
  const __hip_bfloat16* gA[2];
  const __hip_bfloat16* gB;
#pragma unroll
  for (int i2 = 0; i2 < 2; i2++) {
    int sg = i2 * 256 + tid;
    int r = sg >> 2;
    int q = (sg & 3) ^ ((r >> 1) & 3);        // un-swizzle: logical k-granule
    int rowA = mt * BM + r;
    int slot = rowA < n_e ? rowA : n_e - 1;   // clamp tail rows to valid slot
    int tok = idx[e * CAP + slot];
    gA[i2] = xb + tok * DD + q * 8;
  }
  {
    int r = tid >> 2;
    int q = (tid & 3) ^ ((r >> 1) & 3);
    gB = w1t + (e * WW + nt * BN + r) * DD + q * 8;
  }
  short* ldsA0 = As + (wave * 64) * 8;
  short* ldsA1 = As + (256 + wave * 64) * 8;
  short* ldsB  = Bs + (wave * 64) * 8;

  int aoff[4], boff[2];
#pragma unroll
  for (int i2 = 0; i2 < 4; i2++) {
    int ra = wm + i2 * 16 + m16;
    aoff[i2] = (ra * 4 + (qd ^ ((ra >> 1) & 3))) * 8;
  }
#pragma unroll
  for (int i2 = 0; i2 < 2; i2++) {
    int rb = wn + i2 * 16 + m16;
    boff[i2] = (rb * 4 + (qd ^ ((rb >> 1) & 3))) * 8;
  }

  f32x4 zero = {0.f, 0.f, 0.f, 0.f};
  f32x4 acc[4][2];
#pragma unroll
  for (int mi = 0; mi < 4; mi++)
#pragma unroll
    for (int ni = 0; ni < 2; ni++) acc[mi][ni] = zero;

  for (int k0 = 0; k0 < DD; k0 += BK) {
    gload_lds16(gA[0] + k0, ldsA0);
    gload_lds16(gA[1] + k0, ldsA1);
    gload_lds16(gB + k0, ldsB);
    __syncthreads();
    bf16x8 af[4], bfr[2];
#pragma unroll
    for (int i2 = 0; i2 < 4; i2++) af[i2] = *(const bf16x8*)(As + aoff[i2]);
#pragma unroll
    for (int i2 = 0; i2 < 2; i2++) bfr[i2] = *(const bf16x8*)(Bs + boff[i2]);
#pragma unroll
    for (int mi = 0; mi < 4; mi++)
#pragma unroll
      for (int ni = 0; ni < 2; ni++)
        acc[mi][ni] = __builtin_amdgcn_mfma_f32_16x16x32_bf16(
            af[mi], bfr[ni], acc[mi][ni], 0, 0, 0);
    __syncthreads();
  }

  // epilogue: relu^2 -> bf16 act[(e*CAP + slot)][col]
#pragma unroll
  for (int mi = 0; mi < 4; mi++) {
#pragma unroll
    for (int reg = 0; reg < 4; reg++) {
      int rowt = mt * BM + wm + mi * 16 + qd * 4 + reg;
      if (rowt < n_e) {
#pragma unroll
        for (int ni = 0; ni < 2; ni++) {
          float v = acc[mi][ni][reg];
          v = v > 0.f ? v * v : 0.f;
          int col = nt * BN + wn + ni * 16 + m16;
          act[(e * CAP + rowt) * WW + col] = __float2bfloat16(v);
        }
      }
    }
  }
}

// ---------------- grouped GEMM2: y = act @ W2_e (raw bf16 y, no atomics) ----------------
__global__ __launch_bounds__(256) void gemm2_kernel(
    const __hip_bfloat16* __restrict__ act, const __hip_bfloat16* __restrict__ w2t,
    const int* __restrict__ counts, __hip_bfloat16* __restrict__ y)
{
  __shared__ short As[BM * BK];
  __shared__ short Bs[BN * BK];
  int bid = blockIdx.x;
  int e = bid & 7;
  int i = bid >> 3;
  int mt = i >> 4, nt = i & 15;
  int n_e = counts[e];
  if (mt * BM >= n_e) return;

  int tid = threadIdx.x;
  int lane = tid & 63;
  int wave = __builtin_amdgcn_readfirstlane(tid >> 6);
  int wm = (wave >> 1) * 64, wn = (wave & 1) * 32;
  int m16 = lane & 15, qd = lane >> 4;

  const __hip_bfloat16* gA[2];
  const __hip_bfloat16* gB;
#pragma unroll
  for (int i2 = 0; i2 < 2; i2++) {
    int sg = i2 * 256 + tid;
    int r = sg >> 2;
    int q = (sg & 3) ^ ((r >> 1) & 3);
    gA[i2] = act + (e * CAP + mt * BM + r) * WW + q * 8;  // rows >= n_e: garbage, row-isolated
  }
  {
    int r = tid >> 2;
    int q = (tid & 3) ^ ((r >> 1) & 3);
    gB = w2t + (e * DD + nt * BN + r) * WW + q * 8;
  }
  short* ldsA0 = As + (wave * 64) * 8;
  short* ldsA1 = As + (256 + wave * 64) * 8;
  short* ldsB  = Bs + (wave * 64) * 8;

  int aoff[4], boff[2];
#pragma unroll
  for (int i2 = 0; i2 < 4; i2++) {
    int ra = wm + i2 * 16 + m16;
    aoff[i2] = (ra * 4 + (qd ^ ((ra >> 1) & 3))) * 8;
  }
#pragma unroll
  for (int i2 = 0; i2 < 2; i2++) {
    int rb = wn + i2 * 16 + m16;
    boff[i2] = (rb * 4 + (qd ^ ((rb >> 1) & 3))) * 8;
  }

  f32x4 zero = {0.f, 0.f, 0.f, 0.f};
  f32x4 acc[4][2];
#pragma unroll
  for (int mi = 0; mi < 4; mi++)
#pragma unroll
    for (int ni = 0; ni < 2; ni++) acc[mi][ni] = zero;

  for (int k0 = 0; k0 < WW; k0 += BK) {
    gload_lds16(gA[0] + k0, ldsA0);
    gload_lds16(gA[1] + k0, ldsA1);
    gload_lds16(gB + k0, ldsB);
    __syncthreads();
    bf16x8 af[4], bfr[2];
#pragma unroll
    for (int i2 = 0; i2 < 4; i2++) af[i2] = *(const bf16x8*)(As + aoff[i2]);
#pragma unroll
    for (int i2 = 0; i2 < 2; i2++) bfr[i2] = *(const bf16x8*)(Bs + boff[i2]);
#pragma unroll
    for (int mi = 0; mi < 4; mi++)
#pragma unroll
      for (int ni = 0; ni < 2; ni++)
        acc[mi][ni] = __builtin_amdgcn_mfma_f32_16x16x32_bf16(
            af[mi], bfr[ni], acc[mi][ni], 0, 0, 0);
    __syncthreads();
  }

  // epilogue: raw y (weights applied in combine)
#pragma unroll
  for (int mi = 0; mi < 4; mi++) {
#pragma unroll
    for (int reg = 0; reg < 4; reg++) {
      int slot = mt * BM + wm + mi * 16 + qd * 4 + reg;
      if (slot < n_e) {
#pragma unroll
        for (int ni = 0; ni < 2; ni++) {
          int col = nt * BN + wn + ni * 16 + m16;
          y[(e * CAP + slot) * DD + col] = __float2bfloat16(acc[mi][ni][reg]);
        }
      }
    }
  }
}

// ---------------- combine: out[t] = w0*y[slot0] + w1*y[slot1] ----------------
__global__ __launch_bounds__(256) void combine_kernel(
    const __hip_bfloat16* __restrict__ y, const int* __restrict__ tslot,
    const float* __restrict__ wpair, float* __restrict__ out)
{
  int t = blockIdx.x;
  int c = threadIdx.x * 4;
  int s0 = tslot[2 * t], s1 = tslot[2 * t + 1];
  float w0 = wpair[2 * t], w1 = wpair[2 * t + 1];
  const unsigned short* yu = (const unsigned short*)y;
  ushort4 a = *(const ushort4*)(yu + (size_t)s0 * DD + c);
  ushort4 bq = *(const ushort4*)(yu + (size_t)s1 * DD + c);
  f32x4 o;
  o[0] = w0 * bf2f(a.x) + w1 * bf2f(bq.x);
  o[1] = w0 * bf2f(a.y) + w1 * bf2f(bq.y);
  o[2] = w0 * bf2f(a.z) + w1 * bf2f(bq.z);
  o[3] = w0 * bf2f(a.w) + w1 * bf2f(bq.w);
  *(f32x4*)(out + (size_t)t * DD + c) = o;
}

extern "C" void kernel_launch(void* const* d_in, const int* in_sizes, int n_in,
                              void* d_out, int out_size, void* d_ws, size_t ws_size,
                              hipStream_t stream)
{
  const float* x  = (const float*)d_in[0];
  const float* rw = (const float*)d_in[1];
  const float* w1 = (const float*)d_in[2];
  const float* w2 = (const float*)d_in[3];
  float* out = (float*)d_out;

  char* ws = (char*)d_ws;
  __hip_bfloat16* xb  = (__hip_bfloat16*)ws;  ws += (size_t)T_TOKENS * DD * 2;
  __hip_bfloat16* w1t = (__hip_bfloat16*)ws;  ws += (size_t)EE * WW * DD * 2;
  __hip_bfloat16* w2t = (__hip_bfloat16*)ws;  ws += (size_t)EE * DD * WW * 2;
  __hip_bfloat16* act = (__hip_bfloat16*)ws;  ws += (size_t)EE * CAP * WW * 2;
  __hip_bfloat16* y   = (__hip_bfloat16*)ws;  ws += (size_t)EE * CAP * DD * 2;
  int*   counts = (int*)ws;                   ws += 256;
  int*   idx    = (int*)ws;                   ws += (size_t)EE * CAP * 4;
  int*   sel    = (int*)ws;                   ws += (size_t)T_TOKENS * 4;
  int*   tslot  = (int*)ws;                   ws += (size_t)T_TOKENS * 8;
  float* wpair  = (float*)ws;                 ws += (size_t)T_TOKENS * 8;

  // pre: blocks [0,2048) w1 transpose, [2048,4096) w2 transpose, [4096,5120) router
  pre_kernel<<<TR_BLOCKS + T_TOKENS / 4, 256, 0, stream>>>(
      w1, w2, x, rw, w1t, w2t, xb, sel, wpair);
  build_lists<<<1, 1024, 0, stream>>>(sel, counts, idx, tslot);
  gemm1_kernel<<<EE * MT * NT, 256, 0, stream>>>(xb, w1t, counts, idx, act);
  gemm2_kernel<<<EE * MT * NT, 256, 0, stream>>>(act, w2t, counts, y);
  combine_kernel<<<T_TOKENS, 256, 0, stream>>>(y, tslot, wpair, out);
}

// Round 6
// 193.705 us; speedup vs baseline: 1.6077x; 1.0487x over previous
//
#include <hip/hip_runtime.h>
#include <hip/hip_bf16.h>

// MoE MLP (top-2 of 8 experts), T=4096 tokens, D=1024, W=1024.
// R6: (1) GEMM BK 32->64: 16 MFMA/wave/iter (was 8), barrier count halved;
//         XOR swizzle q^(r&7) over 8 granule-cols (uniform 8 lanes/bank-group).
//     (2) build_lists via wave ballots: 512 LDS atomics instead of 8192.
// Retained: XCD map (expert = bid&7), fused transpose+router pre-phase, CAP=1536.

#define T_TOKENS 4096
#define DD 1024
#define EE 8
#define WW 1024
#define CAP 1536          // per-expert capacity (expected ~1024, sigma ~28)
#define BM 128
#define BN 64
#define BK 64
#define MT (CAP / BM)     // 12 m-tiles max per expert
#define NT 16             // 1024/64 n-tiles

typedef short bf16x8 __attribute__((ext_vector_type(8)));
typedef float f32x4 __attribute__((ext_vector_type(4)));

__device__ __forceinline__ void gload_lds16(const void* g, void* l) {
  __builtin_amdgcn_global_load_lds((__attribute__((address_space(1))) void*)(g),
                                   (__attribute__((address_space(3))) void*)(l),
                                   16, 0, 0);
}

__device__ __forceinline__ float bf2f(unsigned short u) {
  union { unsigned int i; float f; } v; v.i = (unsigned int)u << 16; return v.f;
}

// ---------------- fused pre-phase: weight transposes + router ----------------
// blocks [0,2048): w1 transpose; [2048,4096): w2 transpose; [4096,5120): router.
#define TR_BLOCKS 4096
__global__ __launch_bounds__(256) void pre_kernel(
    const float* __restrict__ w1, const float* __restrict__ w2,
    const float* __restrict__ x, const float* __restrict__ rw,
    __hip_bfloat16* __restrict__ w1t, __hip_bfloat16* __restrict__ w2t,
    __hip_bfloat16* __restrict__ xb, int* __restrict__ sel,
    float* __restrict__ wpair)
{
  __shared__ float tile[64][65];
  int b = blockIdx.x;
  if (b < TR_BLOCKS) {
    // ---- transpose part: dst[r*dst_ld+c] = bf16(src[c*src_ld+r]), 64x64 tile ----
    int bx = b & 15;            // dst col tile (16 tiles of 64 over 1024)
    int by = b >> 4;            // 0..255
    const float* src; __hip_bfloat16* dst;
    long src_ld, dst_ld, c0, r0;
    if (by < 128) {
      // w1 [D=1024, E*W=8192] -> w1t [8192, 1024]
      src = w1; dst = w1t; src_ld = EE * WW; dst_ld = DD;
      c0 = (long)bx * 64;       // dst col = src row, 0..1023
      r0 = (long)by * 64;       // dst row = src col, 0..8191
    } else {
      // w2 [E*W, D] expert slice e: [W=1024, D=1024] -> w2t[e] [D=1024, W=1024]
      int z = by - 128;         // 0..127
      int e = z >> 4;           // expert 0..7
      int yy = z & 15;          // dst row tile within expert, 0..15
      src = w2 + (long)e * WW * DD;
      dst = w2t + (long)e * DD * WW;
      src_ld = DD; dst_ld = WW;
      c0 = (long)bx * 64;       // dst col = src row (W dim)
      r0 = (long)yy * 64;       // dst row = src col (D dim)
    }
    int tx = threadIdx.x & 15, ty = threadIdx.x >> 4;
#pragma unroll
    for (int i = 0; i < 4; i++) {
      int sr = ty + 16 * i;
      f32x4 v = *(const f32x4*)(src + (c0 + sr) * src_ld + r0 + tx * 4);
      tile[sr][tx * 4 + 0] = v[0];
      tile[sr][tx * 4 + 1] = v[1];
      tile[sr][tx * 4 + 2] = v[2];
      tile[sr][tx * 4 + 3] = v[3];
    }
    __syncthreads();
#pragma unroll
    for (int i = 0; i < 4; i++) {
      int dr = ty + 16 * i;
      union { __hip_bfloat16 hb[4]; ushort4 u4; } pk;
#pragma unroll
      for (int j = 0; j < 4; j++)
        pk.hb[j] = __float2bfloat16(tile[tx * 4 + j][dr]);
      *(ushort4*)((unsigned short*)dst + (r0 + dr) * dst_ld + c0 + tx * 4) = pk.u4;
    }
  } else {
    // ---- router part: one wave per token, fp32 logits, top-2, no atomics ----
    int lane = threadIdx.x & 63;
    int wave = threadIdx.x >> 6;
    int t = (b - TR_BLOCKS) * 4 + wave;
    const float* xrow = x + (size_t)t * DD;
    float acc[EE];
#pragma unroll
    for (int e = 0; e < EE; e++) acc[e] = 0.f;
#pragma unroll
    for (int i = 0; i < DD / 64; i++) {
      int d = lane + i * 64;
      float xv = xrow[d];
      xb[t * DD + d] = __float2bfloat16(xv);   // fused x -> bf16
#pragma unroll
      for (int e = 0; e < EE; e++) acc[e] += xv * rw[e * DD + d];
    }
#pragma unroll
    for (int e = 0; e < EE; e++) {
#pragma unroll
      for (int off = 32; off > 0; off >>= 1)
        acc[e] += __shfl_down(acc[e], off, 64);
    }
    if (lane == 0) {
      float p[EE];
#pragma unroll
      for (int e = 0; e < EE; e++) p[e] = 1.f / (1.f + expf(-acc[e]));
      // top-2, ties -> lowest index (matches jax.lax.top_k stable ordering)
      int e0 = 0; float b0 = p[0];
      for (int e = 1; e < EE; e++) if (p[e] > b0) { b0 = p[e]; e0 = e; }
      int e1 = -1; float b1 = -1.f;
      for (int e = 0; e < EE; e++) {
        if (e == e0) continue;
        if (p[e] > b1) { b1 = p[e]; e1 = e; }
      }
      float s = b0 + b1 + 1e-20f;
      sel[t] = e0 | (e1 << 8);
      wpair[2 * t]     = b0 / s;
      wpair[2 * t + 1] = b1 / s;
    }
  }
}

// ---------------- build per-expert token lists (1 block, wave-ballot agg) ----------------
__global__ __launch_bounds__(1024) void build_lists(
    const int* __restrict__ sel, int* __restrict__ counts,
    int* __restrict__ idx, int* __restrict__ tslot)
{
  __shared__ int lcnt[EE];
  int tid = threadIdx.x, lane = tid & 63;
  if (tid < EE) lcnt[tid] = 0;
  __syncthreads();
  unsigned long long lower = (1ull << lane) - 1;
#pragma unroll
  for (int j = 0; j < T_TOKENS / 1024; j++) {
    int t = j * 1024 + tid;
    int s = sel[t];
    int e0 = s & 0xff, e1 = (s >> 8) & 0xff;
    int slot0 = 0, slot1 = 0;
#pragma unroll
    for (int e = 0; e < EE; e++) {
      unsigned long long m0 = __ballot(e0 == e);
      unsigned long long m1 = __ballot(e1 == e);
      int c0 = __popcll(m0), c1 = __popcll(m1);
      int base = 0;
      if (lane == 0 && (c0 + c1) > 0) base = atomicAdd(&lcnt[e], c0 + c1);
      base = __shfl(base, 0, 64);
      if (e0 == e) slot0 = base + __popcll(m0 & lower);
      if (e1 == e) slot1 = base + c0 + __popcll(m1 & lower);
    }
    int p0 = e0 * CAP + slot0, p1 = e1 * CAP + slot1;
    idx[p0] = t; idx[p1] = t;
    tslot[2 * t] = p0; tslot[2 * t + 1] = p1;
  }
  __syncthreads();
  if (tid < EE) counts[tid] = lcnt[tid];
}

// ---------------- grouped GEMM1: h = gather(xb) @ W1_e, act = relu(h)^2 ----------------
// XCD map: expert = bid & 7 (round-robin dispatch puts expert e on XCD e;
// B slab 2MB + A slab ~2MB stay L2-resident).
__global__ __launch_bounds__(256) void gemm1_kernel(
    const __hip_bfloat16* __restrict__ xb, const __hip_bfloat16* __restrict__ w1t,
    const int* __restrict__ counts, const int* __restrict__ idx,
    __hip_bfloat16* __restrict__ act)
{
  __shared__ short As[BM * BK];   // 16 KB
  __shared__ short Bs[BN * BK];   // 8 KB
  int bid = blockIdx.x;
  int e = bid & 7;
  int i = bid >> 3;               // 0..MT*NT-1, nt fastest
  int mt = i >> 4, nt = i & 15;
  int n_e = counts[e];
  if (mt * BM >= n_e) return;

  int tid = threadIdx.x;
  int lane = tid & 63;
  int wave = __builtin_amdgcn_readfirstlane(tid >> 6);
  int wm = (wave >> 1) * 64, wn = (wave & 1) * 32;
  int m16 = lane & 15, qd = lane >> 4;

  // staging: granule = 16B (8 bf16); 8 granule-cols/row; slot s -> row s>>3,
  // swizzled col (s&7)^(row&7). A: 4 issues/thread, B: 2.
  const __hip_bfloat16* gA[4];
  const __hip_bfloat16* gB[2];
#pragma unroll
  for (int i2 = 0; i2 < 4; i2++) {
    int s = i2 * 256 + tid;
    int r = s >> 3;
    int q = (s & 7) ^ (r & 7);                // logical k-granule
    int rowA = mt * BM + r;
    int slot = rowA < n_e ? rowA : n_e - 1;   // clamp tail rows to valid slot
    int tok = idx[e * CAP + slot];
    gA[i2] = xb + (size_t)tok * DD + q * 8;
  }
#pragma unroll
  for (int i2 = 0; i2 < 2; i2++) {
    int s = i2 * 256 + tid;
    int r = s >> 3;
    int q = (s & 7) ^ (r & 7);
    gB[i2] = w1t + ((size_t)e * WW + nt * BN + r) * DD + q * 8;
  }
  short* ldsA[4];
  short* ldsB[2];
#pragma unroll
  for (int i2 = 0; i2 < 4; i2++) ldsA[i2] = As + (i2 * 256 + wave * 64) * 8;
#pragma unroll
  for (int i2 = 0; i2 < 2; i2++) ldsB[i2] = Bs + (i2 * 256 + wave * 64) * 8;

  int aoff[4][2], boff[2][2];
#pragma unroll
  for (int i2 = 0; i2 < 4; i2++) {
    int r = wm + i2 * 16 + m16;
#pragma unroll
    for (int h = 0; h < 2; h++)
      aoff[i2][h] = (r * 8 + ((qd + h * 4) ^ (r & 7))) * 8;
  }
#pragma unroll
  for (int j = 0; j < 2; j++) {
    int r = wn + j * 16 + m16;
#pragma unroll
    for (int h = 0; h < 2; h++)
      boff[j][h] = (r * 8 + ((qd + h * 4) ^ (r & 7))) * 8;
  }

  f32x4 zero = {0.f, 0.f, 0.f, 0.f};
  f32x4 acc[4][2];
#pragma unroll
  for (int mi = 0; mi < 4; mi++)
#pragma unroll
    for (int ni = 0; ni < 2; ni++) acc[mi][ni] = zero;

  for (int k0 = 0; k0 < DD; k0 += BK) {
    gload_lds16(gA[0] + k0, ldsA[0]);
    gload_lds16(gA[1] + k0, ldsA[1]);
    gload_lds16(gA[2] + k0, ldsA[2]);
    gload_lds16(gA[3] + k0, ldsA[3]);
    gload_lds16(gB[0] + k0, ldsB[0]);
    gload_lds16(gB[1] + k0, ldsB[1]);
    __syncthreads();
#pragma unroll
    for (int h = 0; h < 2; h++) {
      bf16x8 af[4], bfr[2];
#pragma unroll
      for (int i2 = 0; i2 < 4; i2++) af[i2] = *(const bf16x8*)(As + aoff[i2][h]);
#pragma unroll
      for (int j = 0; j < 2; j++) bfr[j] = *(const bf16x8*)(Bs + boff[j][h]);
#pragma unroll
      for (int mi = 0; mi < 4; mi++)
#pragma unroll
        for (int ni = 0; ni < 2; ni++)
          acc[mi][ni] = __builtin_amdgcn_mfma_f32_16x16x32_bf16(
              af[mi], bfr[ni], acc[mi][ni], 0, 0, 0);
    }
    __syncthreads();
  }

  // epilogue: relu^2 -> bf16 act[(e*CAP + slot)][col]
#pragma unroll
  for (int mi = 0; mi < 4; mi++) {
#pragma unroll
    for (int reg = 0; reg < 4; reg++) {
      int rowt = mt * BM + wm + mi * 16 + qd * 4 + reg;
      if (rowt < n_e) {
#pragma unroll
        for (int ni = 0; ni < 2; ni++) {
          float v = acc[mi][ni][reg];
          v = v > 0.f ? v * v : 0.f;
          int col = nt * BN + wn + ni * 16 + m16;
          act[((size_t)e * CAP + rowt) * WW + col] = __float2bfloat16(v);
        }
      }
    }
  }
}

// ---------------- grouped GEMM2: y = act @ W2_e (raw bf16 y, no atomics) ----------------
__global__ __launch_bounds__(256) void gemm2_kernel(
    const __hip_bfloat16* __restrict__ act, const __hip_bfloat16* __restrict__ w2t,
    const int* __restrict__ counts, __hip_bfloat16* __restrict__ y)
{
  __shared__ short As[BM * BK];
  __shared__ short Bs[BN * BK];
  int bid = blockIdx.x;
  int e = bid & 7;
  int i = bid >> 3;
  int mt = i >> 4, nt = i & 15;
  int n_e = counts[e];
  if (mt * BM >= n_e) return;

  int tid = threadIdx.x;
  int lane = tid & 63;
  int wave = __builtin_amdgcn_readfirstlane(tid >> 6);
  int wm = (wave >> 1) * 64, wn = (wave & 1) * 32;
  int m16 = lane & 15, qd = lane >> 4;

  const __hip_bfloat16* gA[4];
  const __hip_bfloat16* gB[2];
#pragma unroll
  for (int i2 = 0; i2 < 4; i2++) {
    int s = i2 * 256 + tid;
    int r = s >> 3;
    int q = (s & 7) ^ (r & 7);
    gA[i2] = act + ((size_t)e * CAP + mt * BM + r) * WW + q * 8;  // rows >= n_e: garbage, row-isolated
  }
#pragma unroll
  for (int i2 = 0; i2 < 2; i2++) {
    int s = i2 * 256 + tid;
    int r = s >> 3;
    int q = (s & 7) ^ (r & 7);
    gB[i2] = w2t + ((size_t)e * DD + nt * BN + r) * WW + q * 8;
  }
  short* ldsA[4];
  short* ldsB[2];
#pragma unroll
  for (int i2 = 0; i2 < 4; i2++) ldsA[i2] = As + (i2 * 256 + wave * 64) * 8;
#pragma unroll
  for (int i2 = 0; i2 < 2; i2++) ldsB[i2] = Bs + (i2 * 256 + wave * 64) * 8;

  int aoff[4][2], boff[2][2];
#pragma unroll
  for (int i2 = 0; i2 < 4; i2++) {
    int r = wm + i2 * 16 + m16;
#pragma unroll
    for (int h = 0; h < 2; h++)
      aoff[i2][h] = (r * 8 + ((qd + h * 4) ^ (r & 7))) * 8;
  }
#pragma unroll
  for (int j = 0; j < 2; j++) {
    int r = wn + j * 16 + m16;
#pragma unroll
    for (int h = 0; h < 2; h++)
      boff[j][h] = (r * 8 + ((qd + h * 4) ^ (r & 7))) * 8;
  }

  f32x4 zero = {0.f, 0.f, 0.f, 0.f};
  f32x4 acc[4][2];
#pragma unroll
  for (int mi = 0; mi < 4; mi++)
#pragma unroll
    for (int ni = 0; ni < 2; ni++) acc[mi][ni] = zero;

  for (int k0 = 0; k0 < WW; k0 += BK) {
    gload_lds16(gA[0] + k0, ldsA[0]);
    gload_lds16(gA[1] + k0, ldsA[1]);
    gload_lds16(gA[2] + k0, ldsA[2]);
    gload_lds16(gA[3] + k0, ldsA[3]);
    gload_lds16(gB[0] + k0, ldsB[0]);
    gload_lds16(gB[1] + k0, ldsB[1]);
    __syncthreads();
#pragma unroll
    for (int h = 0; h < 2; h++) {
      bf16x8 af[4], bfr[2];
#pragma unroll
      for (int i2 = 0; i2 < 4; i2++) af[i2] = *(const bf16x8*)(As + aoff[i2][h]);
#pragma unroll
      for (int j = 0; j < 2; j++) bfr[j] = *(const bf16x8*)(Bs + boff[j][h]);
#pragma unroll
      for (int mi = 0; mi < 4; mi++)
#pragma unroll
        for (int ni = 0; ni < 2; ni++)
          acc[mi][ni] = __builtin_amdgcn_mfma_f32_16x16x32_bf16(
              af[mi], bfr[ni], acc[mi][ni], 0, 0, 0);
    }
    __syncthreads();
  }

  // epilogue: raw y (weights applied in combine)
#pragma unroll
  for (int mi = 0; mi < 4; mi++) {
#pragma unroll
    for (int reg = 0; reg < 4; reg++) {
      int slot = mt * BM + wm + mi * 16 + qd * 4 + reg;
      if (slot < n_e) {
#pragma unroll
        for (int ni = 0; ni < 2; ni++) {
          int col = nt * BN + wn + ni * 16 + m16;
          y[((size_t)e * CAP + slot) * DD + col] = __float2bfloat16(acc[mi][ni][reg]);
        }
      }
    }
  }
}

// ---------------- combine: out[t] = w0*y[slot0] + w1*y[slot1] ----------------
__global__ __launch_bounds__(256) void combine_kernel(
    const __hip_bfloat16* __restrict__ y, const int* __restrict__ tslot,
    const float* __restrict__ wpair, float* __restrict__ out)
{
  int t = blockIdx.x;
  int c = threadIdx.x * 4;
  int s0 = tslot[2 * t], s1 = tslot[2 * t + 1];
  float w0 = wpair[2 * t], w1 = wpair[2 * t + 1];
  const unsigned short* yu = (const unsigned short*)y;
  ushort4 a = *(const ushort4*)(yu + (size_t)s0 * DD + c);
  ushort4 bq = *(const ushort4*)(yu + (size_t)s1 * DD + c);
  f32x4 o;
  o[0] = w0 * bf2f(a.x) + w1 * bf2f(bq.x);
  o[1] = w0 * bf2f(a.y) + w1 * bf2f(bq.y);
  o[2] = w0 * bf2f(a.z) + w1 * bf2f(bq.z);
  o[3] = w0 * bf2f(a.w) + w1 * bf2f(bq.w);
  *(f32x4*)(out + (size_t)t * DD + c) = o;
}

extern "C" void kernel_launch(void* const* d_in, const int* in_sizes, int n_in,
                              void* d_out, int out_size, void* d_ws, size_t ws_size,
                              hipStream_t stream)
{
  const float* x  = (const float*)d_in[0];
  const float* rw = (const float*)d_in[1];
  const float* w1 = (const float*)d_in[2];
  const float* w2 = (const float*)d_in[3];
  float* out = (float*)d_out;

  char* ws = (char*)d_ws;
  __hip_bfloat16* xb  = (__hip_bfloat16*)ws;  ws += (size_t)T_TOKENS * DD * 2;
  __hip_bfloat16* w1t = (__hip_bfloat16*)ws;  ws += (size_t)EE * WW * DD * 2;
  __hip_bfloat16* w2t = (__hip_bfloat16*)ws;  ws += (size_t)EE * DD * WW * 2;
  __hip_bfloat16* act = (__hip_bfloat16*)ws;  ws += (size_t)EE * CAP * WW * 2;
  __hip_bfloat16* y   = (__hip_bfloat16*)ws;  ws += (size_t)EE * CAP * DD * 2;
  int*   counts = (int*)ws;                   ws += 256;
  int*   idx    = (int*)ws;                   ws += (size_t)EE * CAP * 4;
  int*   sel    = (int*)ws;                   ws += (size_t)T_TOKENS * 4;
  int*   tslot  = (int*)ws;                   ws += (size_t)T_TOKENS * 8;
  float* wpair  = (float*)ws;                 ws += (size_t)T_TOKENS * 8;

  // pre: blocks [0,2048) w1 transpose, [2048,4096) w2 transpose, [4096,5120) router
  pre_kernel<<<TR_BLOCKS + T_TOKENS / 4, 256, 0, stream>>>(
      w1, w2, x, rw, w1t, w2t, xb, sel, wpair);
  build_lists<<<1, 1024, 0, stream>>>(sel, counts, idx, tslot);
  gemm1_kernel<<<EE * MT * NT, 256, 0, stream>>>(xb, w1t, counts, idx, act);
  gemm2_kernel<<<EE * MT * NT, 256, 0, stream>>>(act, w2t, counts, y);
  combine_kernel<<<T_TOKENS, 256, 0, stream>>>(y, tslot, wpair, out);
}